// Round 6
// baseline (264.316 us; speedup 1.0000x reference)
//
#include <hip/hip_runtime.h>

#define NH    16
#define DK    64
#define DIM   1024
#define BATCH 2
#define SEQ   2048
#define MROWS (BATCH*SEQ)   // 4096
#define BK    64
#define QSCALE 0.18033688011112043f   // 0.125 * log2(e): folded into Q projection
#define SENT   -44.0f                 // sentinel in log2 domain; exp2(-44)=5.68e-14
#define PCONST 5.684341886080802e-14f // exp2(-44)

typedef unsigned short bfraw;
typedef __attribute__((ext_vector_type(8))) __bf16 bf16x8;
typedef __attribute__((ext_vector_type(8))) unsigned short u16x8;
typedef __attribute__((ext_vector_type(4))) float f32x4;

__device__ __forceinline__ float bf2f(bfraw u) {
    union { unsigned int i; float f; } x; x.i = ((unsigned int)u) << 16; return x.f;
}
__device__ __forceinline__ bfraw f2bf(float f) {          // RNE
    union { float f; unsigned int i; } x; x.f = f;
    unsigned int r = x.i + 0x7FFFu + ((x.i >> 16) & 1u);
    return (bfraw)(r >> 16);
}
__device__ __forceinline__ bfraw f2bf_trunc(float f) {    // truncate (P only; bias cancels in normalize)
    union { float f; unsigned int i; } x; x.f = f;
    return (bfraw)(x.i >> 16);
}
__device__ __forceinline__ float fexp2(float x) {
#if __has_builtin(__builtin_amdgcn_exp2f)
    return __builtin_amdgcn_exp2f(x);
#else
    return exp2f(x);
#endif
}

// async global->LDS, 16B/lane; lds base is WAVE-uniform (HW adds lane*16B)
__device__ __forceinline__ void gload16(const bfraw* g, bfraw* l) {
#if __has_builtin(__builtin_amdgcn_global_load_lds)
    __builtin_amdgcn_global_load_lds(
        (const __attribute__((address_space(1))) unsigned int*)g,
        (__attribute__((address_space(3))) unsigned int*)l, 16, 0, 0);
#else
    *(u16x8*)(l + (threadIdx.x & 63) * 8) = *(const u16x8*)g;
#endif
}

__device__ __forceinline__ float block_reduce(float val, float* rbuf, int op) {
    const int lane = threadIdx.x & 63, wave = threadIdx.x >> 6;
    #pragma unroll
    for (int off = 32; off; off >>= 1) {
        float o = __shfl_xor(val, off, 64);
        val = op ? (val + o) : fmaxf(val, o);
    }
    if (lane == 0) rbuf[wave] = val;
    __syncthreads();
    float r = op ? (rbuf[0] + rbuf[1] + rbuf[2] + rbuf[3])
                 : fmaxf(fmaxf(rbuf[0], rbuf[1]), fmaxf(rbuf[2], rbuf[3]));
    __syncthreads();
    return r;
}

// ---------------- fp32 -> bf16 convert pass ----------------
__global__ __launch_bounds__(256) void cvt_kernel(
        const float* __restrict__ x0, const float* __restrict__ x1, const float* __restrict__ x2,
        const float* __restrict__ w0, const float* __restrict__ w1, const float* __restrict__ w2,
        const float* __restrict__ w3, bfraw* __restrict__ Xb, bfraw* __restrict__ Wb) {
    const int t = blockIdx.y;
    const float* src; bfraw* dst; int n;
    if (t < 3) { src = (t == 0) ? x0 : (t == 1) ? x1 : x2; dst = Xb + t * (MROWS * DIM); n = MROWS * DIM; }
    else { int u = t - 3; src = (u == 0) ? w0 : (u == 1) ? w1 : (u == 2) ? w2 : w3;
           dst = Wb + u * (DIM * DIM); n = DIM * DIM; }
    int idx = (blockIdx.x * 256 + threadIdx.x) * 8;
    if (idx >= n) return;
    f32x4 a = *(const f32x4*)(src + idx);
    f32x4 b = *(const f32x4*)(src + idx + 4);
    u16x8 o;
    #pragma unroll
    for (int j = 0; j < 4; j++) { o[j] = f2bf(a[j]); o[4 + j] = f2bf(b[j]); }
    *(u16x8*)(dst + idx) = o;
}

// ---------------- 128x128 MFMA GEMM, BK=64, XOR-swizzled LDS ----------------
__device__ __forceinline__ void gemm128(const bfraw* __restrict__ A, const bfraw* __restrict__ B,
                                        int m0, int n0, f32x4 acc[4][4]) {
    __shared__ __align__(16) bfraw As[128 * BK];
    __shared__ __align__(16) bfraw Bs[128 * BK];
    const int tid = threadIdx.x, wave = tid >> 6;
    const int lane = tid & 63, lrow = lane & 15, quad = lane >> 4;
    const int wy = wave >> 1, wx = wave & 1;
    const int swz = lrow & 7;
    const int srow = tid >> 3;
    const int schunk = ((tid & 7) ^ (srow & 7)) << 3;
    const bfraw* ga[4]; const bfraw* gb[4];
    #pragma unroll
    for (int g = 0; g < 4; g++) {
        ga[g] = A + (m0 + g * 32 + srow) * DIM + schunk;
        gb[g] = B + (n0 + g * 32 + srow) * DIM + schunk;
    }
    bfraw* la = As + wave * 512;
    bfraw* lb = Bs + wave * 512;

    #pragma unroll
    for (int i = 0; i < 4; i++)
        #pragma unroll
        for (int j = 0; j < 4; j++) { f32x4 z = {0.f, 0.f, 0.f, 0.f}; acc[i][j] = z; }

    for (int k0 = 0; k0 < DIM; k0 += BK) {
        __syncthreads();
        #pragma unroll
        for (int g = 0; g < 4; g++) gload16(ga[g] + k0, la + g * 2048);
        #pragma unroll
        for (int g = 0; g < 4; g++) gload16(gb[g] + k0, lb + g * 2048);
        __syncthreads();
        #pragma unroll
        for (int ks = 0; ks < 2; ks++) {
            const int c = (ks << 2) | quad;
            bf16x8 af[4], bfg[4];
            #pragma unroll
            for (int mi = 0; mi < 4; mi++)
                af[mi] = *(const bf16x8*)&As[(wy * 64 + mi * 16 + lrow) * BK + ((c ^ swz) << 3)];
            #pragma unroll
            for (int ni = 0; ni < 4; ni++)
                bfg[ni] = *(const bf16x8*)&Bs[(wx * 64 + ni * 16 + lrow) * BK + ((c ^ swz) << 3)];
            #pragma unroll
            for (int mi = 0; mi < 4; mi++)
                #pragma unroll
                for (int ni = 0; ni < 4; ni++)
                    acc[mi][ni] = __builtin_amdgcn_mfma_f32_16x16x32_bf16(af[mi], bfg[ni], acc[mi][ni], 0, 0, 0);
        }
    }
}

// ---------------- QKV projection ----------------
__global__ __launch_bounds__(256) void qkv_gemm(
        const bfraw* __restrict__ Xb, const bfraw* __restrict__ Wb,
        bfraw* __restrict__ Qp, bfraw* __restrict__ Kp, bfraw* __restrict__ Vt) {
    const int which = blockIdx.z;
    const bfraw* A = Xb + which * (MROWS * DIM);
    const bfraw* B = Wb + which * (DIM * DIM);
    bfraw* O = (which == 0) ? Qp : (which == 1) ? Kp : Vt;
    const int m0 = blockIdx.x * 128, n0 = blockIdx.y * 128;
    f32x4 acc[4][4];
    gemm128(A, B, m0, n0, acc);
    const int lane = threadIdx.x & 63, wave = threadIdx.x >> 6;
    const int lrow = lane & 15, quad = lane >> 4;
    const int wy = wave >> 1, wx = wave & 1;
    const float scale = (which == 0) ? QSCALE : 1.0f;
    #pragma unroll
    for (int mi = 0; mi < 4; mi++)
        #pragma unroll
        for (int ni = 0; ni < 4; ni++)
            #pragma unroll
            for (int i = 0; i < 4; i++) {
                int m = m0 + wy * 64 + mi * 16 + quad * 4 + i;
                int n = n0 + wx * 64 + ni * 16 + lrow;
                int b = m >> 11, s = m & (SEQ - 1), h = n >> 6, kk = n & (DK - 1);
                bfraw v = f2bf(acc[mi][ni][i] * scale);
                if (which == 2) O[(((b * NH + h) * DK) + kk) * SEQ + s] = v;
                else            O[(((b * NH + h) * SEQ) + s) * DK + kk] = v;
            }
}

// ---------------- V tile-boundary prefix sums ----------------
__global__ __launch_bounds__(256) void vsum_kernel(const bfraw* __restrict__ Vt,
                                                   float* __restrict__ Scum) {
    __shared__ float Ts[32][65];
    const int bh = blockIdx.x, tid = threadIdx.x;
    const int d = tid & 63, part = tid >> 6;
    const bfraw* vrow = Vt + (bh * DK + d) * SEQ;
    for (int qt = part * 8; qt < part * 8 + 8; qt++) {
        float s = 0.f;
        #pragma unroll
        for (int j = 0; j < 64; j += 8) {
            u16x8 v = *(const u16x8*)(vrow + qt * 64 + j);
            #pragma unroll
            for (int e = 0; e < 8; e++) s += bf2f(v[e]);
        }
        Ts[qt][d] = s;
    }
    __syncthreads();
    if (tid < 64) {
        float run = 0.f;
        for (int qt = 0; qt < 32; qt++) {
            Scum[(bh * 32 + qt) * 64 + tid] = run;
            run += Ts[qt][tid];
        }
    }
}

// ---------------- flash MFMA attention: 128 q-rows/block, 32/wave ----------------
// grid (bh=32, y=16): all q-tiles of one (b,h) share an XCD. K/V staged via
// global_load_lds into XOR-swizzled unpadded LDS (conflict-free frag reads).
// Below-diagonal contribution folded analytically via per-wave Scum boundary.
__global__ __launch_bounds__(256) void attn_flash(
        const bfraw* __restrict__ Qp, const bfraw* __restrict__ Kp, const bfraw* __restrict__ Vt,
        const float* __restrict__ Scum, const int* __restrict__ mask, bfraw* __restrict__ Ctx) {
    __shared__ __align__(16) bfraw Ks[64 * 64];
    __shared__ __align__(16) bfraw Vs[64 * 64];
    __shared__ __align__(16) bfraw Pw[4][32 * 68];
    __shared__ unsigned short Mk[SEQ];
    const int bh = blockIdx.x, yy = blockIdx.y;
    const int qt = (yy & 1) ? (15 - (yy >> 1)) : (yy >> 1);   // pair long+short qt on a CU
    const int b = bh >> 4, h = bh & 15;
    const int tid = threadIdx.x, wave = tid >> 6, lane = tid & 63;
    const int lrow = lane & 15, quad = lane >> 4;
    const int baseK = ((b * NH + h) * SEQ) * DK;
    const int baseV = ((b * NH + h) * DK) * SEQ;
    const int blockDiag = qt * 128;
    const int qbase = blockDiag + wave * 32;
    const int tW = qt * 2 + (wave >> 1);              // per-wave 64-boundary index
    const int wstart = blockDiag + (wave >> 1) * 64;  // first tile this wave computes
    // staging: lane -> row lane>>3 (of 8), chunk (lane&7) XOR row parity
    const int srow8 = lane >> 3;
    const int gchunk = ((lane & 7) ^ srow8) << 3;

    for (int i = tid; i < SEQ; i += 256) Mk[i] = (unsigned short)(mask[b * SEQ + i] != 0);

    bf16x8 qf[2][2];   // [set][ks]
    #pragma unroll
    for (int set = 0; set < 2; set++)
        #pragma unroll
        for (int ks = 0; ks < 2; ks++)
            qf[set][ks] = *(const bf16x8*)(Qp + baseK + (qbase + set * 16 + lrow) * DK + ks * 32 + quad * 8);

    f32x4 Oa[2][4]; float lsum[2][4];
    #pragma unroll
    for (int n = 0; n < 4; n++) {
        float base = PCONST * Scum[(bh * 32 + tW) * 64 + n * 16 + lrow];
        #pragma unroll
        for (int set = 0; set < 2; set++) {
            #pragma unroll
            for (int i = 0; i < 4; i++) Oa[set][n][i] = base;
        }
    }
    #pragma unroll
    for (int set = 0; set < 2; set++)
        #pragma unroll
        for (int i = 0; i < 4; i++) lsum[set][i] = 0.f;

    for (int kt0 = blockDiag; kt0 < SEQ; kt0 += 64) {
        __syncthreads();                          // prior tile's LDS reads done (also covers Mk 1st iter)
        #pragma unroll
        for (int r = 0; r < 2; r++) {
            const int row0 = r * 32 + wave * 8;
            gload16(Kp + baseK + (kt0 + row0 + srow8) * DK + gchunk, Ks + row0 * 64);
            gload16(Vt + baseV + (row0 + srow8) * SEQ + kt0 + gchunk, Vs + row0 * 64);
        }
        __syncthreads();                          // barrier drains vmcnt

        if (kt0 >= wstart) {
            // K frags (shared by both q-sets)
            bf16x8 kf[2][4];
            #pragma unroll
            for (int n = 0; n < 4; n++) {
                const int s = n * 16 + lrow;
                #pragma unroll
                for (int ks = 0; ks < 2; ks++)
                    kf[ks][n] = *(const bf16x8*)&Ks[s * 64 + ((((ks << 2) | quad) ^ (s & 7)) << 3)];
            }
            f32x4 S[2][4];
            #pragma unroll
            for (int set = 0; set < 2; set++)
                #pragma unroll
                for (int n = 0; n < 4; n++) {
                    f32x4 z = {0.f, 0.f, 0.f, 0.f};
                    z = __builtin_amdgcn_mfma_f32_16x16x32_bf16(qf[set][0], kf[0][n], z, 0, 0, 0);
                    S[set][n] = __builtin_amdgcn_mfma_f32_16x16x32_bf16(qf[set][1], kf[1][n], S[set][n] = z, 0, 0, 0);
                }

            const bool diagzone = (kt0 < blockDiag + 128);
            #pragma unroll
            for (int set = 0; set < 2; set++) {
                #pragma unroll
                for (int n = 0; n < 4; n++) {
                    const int s = kt0 + n * 16 + lrow;
                    const bool mk = (Mk[s] != 0);
                    #pragma unroll
                    for (int i = 0; i < 4; i++) {
                        bool valid = diagzone ? (mk && (s > qbase + set * 16 + quad * 4 + i)) : mk;
                        float p = fexp2(valid ? S[set][n][i] : SENT);
                        lsum[set][i] += p;
                        Pw[wave][(set * 16 + quad * 4 + i) * 68 + n * 16 + lrow] = f2bf_trunc(p);
                    }
                }
            }

            // V frags + P frags, PV accumulate
            bf16x8 vf[2][4];
            #pragma unroll
            for (int n = 0; n < 4; n++) {
                const int d = n * 16 + lrow;
                #pragma unroll
                for (int ks = 0; ks < 2; ks++)
                    vf[ks][n] = *(const bf16x8*)&Vs[d * 64 + ((((ks << 2) | quad) ^ (d & 7)) << 3)];
            }
            bf16x8 pf[2][2];
            #pragma unroll
            for (int set = 0; set < 2; set++)
                #pragma unroll
                for (int ks = 0; ks < 2; ks++)
                    pf[set][ks] = *(const bf16x8*)&Pw[wave][(set * 16 + lrow) * 68 + ks * 32 + quad * 8];
            #pragma unroll
            for (int set = 0; set < 2; set++)
                #pragma unroll
                for (int n = 0; n < 4; n++) {
                    Oa[set][n] = __builtin_amdgcn_mfma_f32_16x16x32_bf16(pf[set][0], vf[0][n], Oa[set][n], 0, 0, 0);
                    Oa[set][n] = __builtin_amdgcn_mfma_f32_16x16x32_bf16(pf[set][1], vf[1][n], Oa[set][n], 0, 0, 0);
                }
        }
    }

    #pragma unroll
    for (int set = 0; set < 2; set++) {
        float inv[4];
        #pragma unroll
        for (int i = 0; i < 4; i++) {
            float r = lsum[set][i];
            #pragma unroll
            for (int off = 1; off < 16; off <<= 1) r += __shfl_xor(r, off, 64);
            inv[i] = 1.0f / (r + (float)(tW * 64) * PCONST);
        }
        #pragma unroll
        for (int n = 0; n < 4; n++)
            #pragma unroll
            for (int i = 0; i < 4; i++)
                Ctx[(b * SEQ + qbase + set * 16 + quad * 4 + i) * DIM + h * DK + n * 16 + lrow]
                    = f2bf(Oa[set][n][i] * inv[i]);
    }
}

// ---------------- output projection ----------------
__global__ __launch_bounds__(256) void out_gemm(
        const bfraw* __restrict__ Ctx, const bfraw* __restrict__ WoB, float* __restrict__ C) {
    const int m0 = blockIdx.x * 128, n0 = blockIdx.y * 128;
    f32x4 acc[4][4];
    gemm128(Ctx, WoB, m0, n0, acc);
    const int lane = threadIdx.x & 63, wave = threadIdx.x >> 6;
    const int lrow = lane & 15, quad = lane >> 4;
    const int wy = wave >> 1, wx = wave & 1;
    #pragma unroll
    for (int mi = 0; mi < 4; mi++)
        #pragma unroll
        for (int ni = 0; ni < 4; ni++)
            #pragma unroll
            for (int i = 0; i < 4; i++) {
                int m = m0 + wy * 64 + mi * 16 + quad * 4 + i;
                int n = n0 + wx * 64 + ni * 16 + lrow;
                C[m * DIM + n] = acc[mi][ni][i];
            }
}

// ---------------- residual + LayerNorm (fp32) ----------------
__global__ __launch_bounds__(256) void ln_kernel(
        const float* __restrict__ C, const float* __restrict__ Xq,
        const float* __restrict__ gamma, const float* __restrict__ beta,
        float* __restrict__ out) {
    __shared__ float rbuf[4];
    const int m = blockIdx.x, tid = threadIdx.x;
    const float* crow = C + m * DIM;
    const float* xrow = Xq + m * DIM;
    float v[4]; float s = 0.f, s2 = 0.f;
    #pragma unroll
    for (int i = 0; i < 4; i++) {
        int d = tid + (i << 8);
        float x = crow[d] + xrow[d];
        v[i] = x; s += x; s2 += x * x;
    }
    float S  = block_reduce(s,  rbuf, 1);
    float S2 = block_reduce(s2, rbuf, 1);
    float mu  = S * (1.0f / DIM);
    float var = S2 * (1.0f / DIM) - mu * mu;
    float rstd = rsqrtf(var + 1e-5f);
    #pragma unroll
    for (int i = 0; i < 4; i++) {
        int d = tid + (i << 8);
        out[m * DIM + d] = (v[i] - mu) * rstd * gamma[d] + beta[d];
    }
}

extern "C" void kernel_launch(void* const* d_in, const int* in_sizes, int n_in,
                              void* d_out, int out_size, void* d_ws, size_t ws_size,
                              hipStream_t stream) {
    const float* Xq    = (const float*)d_in[0];
    const float* Xk    = (const float*)d_in[1];
    const float* Xv    = (const float*)d_in[2];
    const int*   mask  = (const int*)  d_in[3];
    const float* Wq    = (const float*)d_in[4];
    const float* Wk    = (const float*)d_in[5];
    const float* Wv    = (const float*)d_in[6];
    const float* Wo    = (const float*)d_in[7];
    const float* gamma = (const float*)d_in[8];
    const float* beta  = (const float*)d_in[9];
    float* out = (float*)d_out;

    char* ws = (char*)d_ws;
    bfraw* Xb   = (bfraw*)(ws);
    bfraw* Wb   = (bfraw*)(ws + (24u << 20));
    bfraw* Qp   = (bfraw*)(ws + (32u << 20));
    bfraw* Kp   = (bfraw*)(ws + (40u << 20));
    bfraw* Vt   = (bfraw*)(ws + (48u << 20));
    bfraw* Ctx  = (bfraw*)(ws + (56u << 20));
    float* C    = (float*)(ws);
    float* Scum = (float*)(ws + (16u << 20));

    dim3 blk(256);
    cvt_kernel<<<dim3(MROWS * DIM / (256 * 8), 7), blk, 0, stream>>>(Xq, Xk, Xv, Wq, Wk, Wv, Wo, Xb, Wb);
    qkv_gemm  <<<dim3(MROWS / 128, DIM / 128, 3),  blk, 0, stream>>>(Xb, Wb, Qp, Kp, Vt);
    vsum_kernel<<<dim3(BATCH * NH),                blk, 0, stream>>>(Vt, Scum);
    attn_flash<<<dim3(BATCH * NH, SEQ / 128),      blk, 0, stream>>>(Qp, Kp, Vt, Scum, mask, Ctx);
    out_gemm  <<<dim3(MROWS / 128, DIM / 128),     blk, 0, stream>>>(Ctx, Wb + 3 * (DIM * DIM), C);
    ln_kernel <<<dim3(MROWS),                      blk, 0, stream>>>(C, Xq, gamma, beta, out);
}

// Round 7
// 236.007 us; speedup vs baseline: 1.1200x; 1.1200x over previous
//
#include <hip/hip_runtime.h>

#define NH    16
#define DK    64
#define DIM   1024
#define BATCH 2
#define SEQ   2048
#define MROWS (BATCH*SEQ)   // 4096
#define BK    64
#define QSCALE 0.18033688011112043f   // 0.125 * log2(e): folded into Q projection
#define SENT   -44.0f                 // sentinel in log2 domain; exp2(-44)=5.68e-14
#define PCONST 5.684341886080802e-14f // exp2(-44)

typedef unsigned short bfraw;
typedef __attribute__((ext_vector_type(8))) __bf16 bf16x8;
typedef __attribute__((ext_vector_type(8))) unsigned short u16x8;
typedef __attribute__((ext_vector_type(4))) float f32x4;

__device__ __forceinline__ float bf2f(bfraw u) {
    union { unsigned int i; float f; } x; x.i = ((unsigned int)u) << 16; return x.f;
}
__device__ __forceinline__ bfraw f2bf(float f) {          // RNE
    union { float f; unsigned int i; } x; x.f = f;
    unsigned int r = x.i + 0x7FFFu + ((x.i >> 16) & 1u);
    return (bfraw)(r >> 16);
}
__device__ __forceinline__ bfraw f2bf_trunc(float f) {    // truncate (P only; bias cancels in normalize)
    union { float f; unsigned int i; } x; x.f = f;
    return (bfraw)(x.i >> 16);
}
__device__ __forceinline__ float fexp2(float x) {
#if __has_builtin(__builtin_amdgcn_exp2f)
    return __builtin_amdgcn_exp2f(x);
#else
    return exp2f(x);
#endif
}

// async global->LDS, 16B/lane; lds base is WAVE-uniform (HW adds lane*16B)
__device__ __forceinline__ void gload16(const bfraw* g, bfraw* l) {
#if __has_builtin(__builtin_amdgcn_global_load_lds)
    __builtin_amdgcn_global_load_lds(
        (const __attribute__((address_space(1))) unsigned int*)g,
        (__attribute__((address_space(3))) unsigned int*)l, 16, 0, 0);
#else
    *(u16x8*)(l + (threadIdx.x & 63) * 8) = *(const u16x8*)g;
#endif
}

__device__ __forceinline__ float block_reduce(float val, float* rbuf, int op) {
    const int lane = threadIdx.x & 63, wave = threadIdx.x >> 6;
    #pragma unroll
    for (int off = 32; off; off >>= 1) {
        float o = __shfl_xor(val, off, 64);
        val = op ? (val + o) : fmaxf(val, o);
    }
    if (lane == 0) rbuf[wave] = val;
    __syncthreads();
    float r = op ? (rbuf[0] + rbuf[1] + rbuf[2] + rbuf[3])
                 : fmaxf(fmaxf(rbuf[0], rbuf[1]), fmaxf(rbuf[2], rbuf[3]));
    __syncthreads();
    return r;
}

// ---------------- fp32 -> bf16 convert pass ----------------
__global__ __launch_bounds__(256) void cvt_kernel(
        const float* __restrict__ x0, const float* __restrict__ x1, const float* __restrict__ x2,
        const float* __restrict__ w0, const float* __restrict__ w1, const float* __restrict__ w2,
        const float* __restrict__ w3, bfraw* __restrict__ Xb, bfraw* __restrict__ Wb) {
    const int t = blockIdx.y;
    const float* src; bfraw* dst; int n;
    if (t < 3) { src = (t == 0) ? x0 : (t == 1) ? x1 : x2; dst = Xb + t * (MROWS * DIM); n = MROWS * DIM; }
    else { int u = t - 3; src = (u == 0) ? w0 : (u == 1) ? w1 : (u == 2) ? w2 : w3;
           dst = Wb + u * (DIM * DIM); n = DIM * DIM; }
    int idx = (blockIdx.x * 256 + threadIdx.x) * 8;
    if (idx >= n) return;
    f32x4 a = *(const f32x4*)(src + idx);
    f32x4 b = *(const f32x4*)(src + idx + 4);
    u16x8 o;
    #pragma unroll
    for (int j = 0; j < 4; j++) { o[j] = f2bf(a[j]); o[4 + j] = f2bf(b[j]); }
    *(u16x8*)(dst + idx) = o;
}

// ---------------- 128x128 MFMA GEMM, BK=64, XOR-swizzled LDS ----------------
__device__ __forceinline__ void gemm128(const bfraw* __restrict__ A, const bfraw* __restrict__ B,
                                        int m0, int n0, f32x4 acc[4][4]) {
    __shared__ __align__(16) bfraw As[128 * BK];
    __shared__ __align__(16) bfraw Bs[128 * BK];
    const int tid = threadIdx.x, wave = tid >> 6;
    const int lane = tid & 63, lrow = lane & 15, quad = lane >> 4;
    const int wy = wave >> 1, wx = wave & 1;
    const int swz = lrow & 7;
    const int srow = tid >> 3;
    const int schunk = ((tid & 7) ^ (srow & 7)) << 3;
    const bfraw* ga[4]; const bfraw* gb[4];
    #pragma unroll
    for (int g = 0; g < 4; g++) {
        ga[g] = A + (m0 + g * 32 + srow) * DIM + schunk;
        gb[g] = B + (n0 + g * 32 + srow) * DIM + schunk;
    }
    bfraw* la = As + wave * 512;
    bfraw* lb = Bs + wave * 512;

    #pragma unroll
    for (int i = 0; i < 4; i++)
        #pragma unroll
        for (int j = 0; j < 4; j++) { f32x4 z = {0.f, 0.f, 0.f, 0.f}; acc[i][j] = z; }

    for (int k0 = 0; k0 < DIM; k0 += BK) {
        __syncthreads();
        #pragma unroll
        for (int g = 0; g < 4; g++) gload16(ga[g] + k0, la + g * 2048);
        #pragma unroll
        for (int g = 0; g < 4; g++) gload16(gb[g] + k0, lb + g * 2048);
        __syncthreads();
        #pragma unroll
        for (int ks = 0; ks < 2; ks++) {
            const int c = (ks << 2) | quad;
            bf16x8 af[4], bfg[4];
            #pragma unroll
            for (int mi = 0; mi < 4; mi++)
                af[mi] = *(const bf16x8*)&As[(wy * 64 + mi * 16 + lrow) * BK + ((c ^ swz) << 3)];
            #pragma unroll
            for (int ni = 0; ni < 4; ni++)
                bfg[ni] = *(const bf16x8*)&Bs[(wx * 64 + ni * 16 + lrow) * BK + ((c ^ swz) << 3)];
            #pragma unroll
            for (int mi = 0; mi < 4; mi++)
                #pragma unroll
                for (int ni = 0; ni < 4; ni++)
                    acc[mi][ni] = __builtin_amdgcn_mfma_f32_16x16x32_bf16(af[mi], bfg[ni], acc[mi][ni], 0, 0, 0);
        }
    }
}

// ---------------- QKV projection ----------------
__global__ __launch_bounds__(256) void qkv_gemm(
        const bfraw* __restrict__ Xb, const bfraw* __restrict__ Wb,
        bfraw* __restrict__ Qp, bfraw* __restrict__ Kp, bfraw* __restrict__ Vt) {
    const int which = blockIdx.z;
    const bfraw* A = Xb + which * (MROWS * DIM);
    const bfraw* B = Wb + which * (DIM * DIM);
    bfraw* O = (which == 0) ? Qp : (which == 1) ? Kp : Vt;
    const int m0 = blockIdx.x * 128, n0 = blockIdx.y * 128;
    f32x4 acc[4][4];
    gemm128(A, B, m0, n0, acc);
    const int lane = threadIdx.x & 63, wave = threadIdx.x >> 6;
    const int lrow = lane & 15, quad = lane >> 4;
    const int wy = wave >> 1, wx = wave & 1;
    const float scale = (which == 0) ? QSCALE : 1.0f;
    #pragma unroll
    for (int mi = 0; mi < 4; mi++)
        #pragma unroll
        for (int ni = 0; ni < 4; ni++)
            #pragma unroll
            for (int i = 0; i < 4; i++) {
                int m = m0 + wy * 64 + mi * 16 + quad * 4 + i;
                int n = n0 + wx * 64 + ni * 16 + lrow;
                int b = m >> 11, s = m & (SEQ - 1), h = n >> 6, kk = n & (DK - 1);
                bfraw v = f2bf(acc[mi][ni][i] * scale);
                if (which == 2) O[(((b * NH + h) * DK) + kk) * SEQ + s] = v;
                else            O[(((b * NH + h) * SEQ) + s) * DK + kk] = v;
            }
}

// ---------------- V tile-boundary prefix sums ----------------
__global__ __launch_bounds__(256) void vsum_kernel(const bfraw* __restrict__ Vt,
                                                   float* __restrict__ Scum) {
    __shared__ float Ts[32][65];
    const int bh = blockIdx.x, tid = threadIdx.x;
    const int d = tid & 63, part = tid >> 6;
    const bfraw* vrow = Vt + (bh * DK + d) * SEQ;
    for (int qt = part * 8; qt < part * 8 + 8; qt++) {
        float s = 0.f;
        #pragma unroll
        for (int j = 0; j < 64; j += 8) {
            u16x8 v = *(const u16x8*)(vrow + qt * 64 + j);
            #pragma unroll
            for (int e = 0; e < 8; e++) s += bf2f(v[e]);
        }
        Ts[qt][d] = s;
    }
    __syncthreads();
    if (tid < 64) {
        float run = 0.f;
        for (int qt = 0; qt < 32; qt++) {
            Scum[(bh * 32 + qt) * 64 + tid] = run;
            run += Ts[qt][tid];
        }
    }
}

// ---------------- flash MFMA attention (r5 structure + swizzled LDS) ----------------
// grid (bh=32, qt'=32): linear%8 = bh%8 -> all q-tiles of one (b,h) share an XCD.
// Register staging (loads issue early, pipeline across co-resident blocks) into
// XOR-swizzled unpadded 64x64 K/V LDS -> conflict-free ds_read_b128 frag reads.
// qt permutation balances work across the 4 blocks stacked on each CU.
__global__ __launch_bounds__(256) void attn_flash(
        const bfraw* __restrict__ Qp, const bfraw* __restrict__ Kp, const bfraw* __restrict__ Vt,
        const float* __restrict__ Scum, const int* __restrict__ mask, bfraw* __restrict__ Ctx) {
    __shared__ __align__(16) bfraw Ks[64 * 64];
    __shared__ __align__(16) bfraw Vs[64 * 64];
    __shared__ __align__(16) bfraw Pw[4][16 * 68];
    __shared__ unsigned short Mk[SEQ];
    const int bh = blockIdx.x, yy = blockIdx.y;
    const int gg = yy >> 3, jj = yy & 7;   // CU-stacked groups {j,31-j,8+j,23-j}: const total work
    const int qt = (gg == 0) ? jj : (gg == 1) ? (31 - jj) : (gg == 2) ? (8 + jj) : (23 - jj);
    const int b = bh >> 4, h = bh & 15;
    const int tid = threadIdx.x, wave = tid >> 6, lane = tid & 63;
    const int lrow = lane & 15, quad = lane >> 4;
    const int baseK = ((b * NH + h) * SEQ) * DK;
    const int baseV = ((b * NH + h) * DK) * SEQ;
    const int qbase = qt * 64 + wave * 16;
    const int diagKt = qt * 64;
    // staging: row ldr (0..63), global chunk pair {cg0, cg0+1} (8 elems each),
    // LDS chunk = global chunk ^ (row&7)
    const int ldr = tid >> 2;
    const int cg0 = (tid & 3) << 1;
    const int ldc = cg0 << 3;
    const int e7 = ldr & 7;
    const int cl0 = ((cg0 ^ e7) << 3), cl1 = (((cg0 | 1) ^ e7) << 3);

    for (int i = tid; i < SEQ; i += 256) Mk[i] = (unsigned short)(mask[b * SEQ + i] != 0);

    bf16x8 qf[2];
    qf[0] = *(const bf16x8*)(Qp + baseK + (qbase + lrow) * DK + quad * 8);
    qf[1] = *(const bf16x8*)(Qp + baseK + (qbase + lrow) * DK + 32 + quad * 8);

    f32x4 O[4]; float lsum[4];
    #pragma unroll
    for (int n = 0; n < 4; n++) {
        float base = PCONST * Scum[(bh * 32 + qt) * 64 + n * 16 + lrow];
        #pragma unroll
        for (int i = 0; i < 4; i++) O[n][i] = base;
    }
    #pragma unroll
    for (int i = 0; i < 4; i++) lsum[i] = 0.f;

    __syncthreads();                                    // Mk visible

    for (int kt0 = diagKt; kt0 < SEQ; kt0 += 64) {
        u16x8 k0 = *(const u16x8*)(Kp + baseK + (kt0 + ldr) * DK + ldc);
        u16x8 k1 = *(const u16x8*)(Kp + baseK + (kt0 + ldr) * DK + ldc + 8);
        u16x8 v0 = *(const u16x8*)(Vt + baseV + ldr * SEQ + kt0 + ldc);
        u16x8 v1 = *(const u16x8*)(Vt + baseV + ldr * SEQ + kt0 + ldc + 8);
        __syncthreads();                                // prior tile's LDS reads done
        *(u16x8*)&Ks[ldr * 64 + cl0] = k0;
        *(u16x8*)&Ks[ldr * 64 + cl1] = k1;
        *(u16x8*)&Vs[ldr * 64 + cl0] = v0;
        *(u16x8*)&Vs[ldr * 64 + cl1] = v1;
        __syncthreads();

        f32x4 S[4];
        #pragma unroll
        for (int n = 0; n < 4; n++) {
            const int s = n * 16 + lrow;
            f32x4 z = {0.f, 0.f, 0.f, 0.f};
            #pragma unroll
            for (int ks = 0; ks < 2; ks++) {
                bf16x8 kb = *(const bf16x8*)&Ks[s * 64 + ((((ks << 2) | quad) ^ (s & 7)) << 3)];
                z = __builtin_amdgcn_mfma_f32_16x16x32_bf16(qf[ks], kb, z, 0, 0, 0);
            }
            S[n] = z;
        }

        float p[4][4];
        if (kt0 == diagKt) {                            // diagonal tile: full causal compare
            #pragma unroll
            for (int n = 0; n < 4; n++) {
                int s = kt0 + n * 16 + lrow;
                bool mk = (Mk[s] != 0);
                #pragma unroll
                for (int i = 0; i < 4; i++) {
                    bool valid = mk && (s > qbase + quad * 4 + i);
                    p[n][i] = fexp2(valid ? S[n][i] : SENT);
                }
            }
        } else {                                        // strictly-future: padding mask only
            #pragma unroll
            for (int n = 0; n < 4; n++) {
                bool mk = (Mk[kt0 + n * 16 + lrow] != 0);
                #pragma unroll
                for (int i = 0; i < 4; i++) p[n][i] = fexp2(mk ? S[n][i] : SENT);
            }
        }

        #pragma unroll
        for (int i = 0; i < 4; i++) lsum[i] += (p[0][i] + p[1][i]) + (p[2][i] + p[3][i]);

        #pragma unroll
        for (int n = 0; n < 4; n++)
            #pragma unroll
            for (int i = 0; i < 4; i++)
                Pw[wave][(quad * 4 + i) * 68 + n * 16 + lrow] = f2bf_trunc(p[n][i]);

        bf16x8 pa0 = *(const bf16x8*)&Pw[wave][lrow * 68 + quad * 8];
        bf16x8 pa1 = *(const bf16x8*)&Pw[wave][lrow * 68 + 32 + quad * 8];
        #pragma unroll
        for (int n = 0; n < 4; n++) {
            const int d = n * 16 + lrow;
            #pragma unroll
            for (int ks = 0; ks < 2; ks++) {
                bf16x8 vb = *(const bf16x8*)&Vs[d * 64 + ((((ks << 2) | quad) ^ (d & 7)) << 3)];
                O[n] = __builtin_amdgcn_mfma_f32_16x16x32_bf16(ks ? pa1 : pa0, vb, O[n], 0, 0, 0);
            }
        }
    }

    float inv[4];
    #pragma unroll
    for (int i = 0; i < 4; i++) {
        float r = lsum[i];
        #pragma unroll
        for (int off = 1; off < 16; off <<= 1) r += __shfl_xor(r, off, 64);
        inv[i] = 1.0f / (r + (float)diagKt * PCONST);
    }
    #pragma unroll
    for (int n = 0; n < 4; n++)
        #pragma unroll
        for (int i = 0; i < 4; i++)
            Ctx[(b * SEQ + qbase + quad * 4 + i) * DIM + h * DK + n * 16 + lrow] = f2bf(O[n][i] * inv[i]);
}

// ---------------- output projection ----------------
__global__ __launch_bounds__(256) void out_gemm(
        const bfraw* __restrict__ Ctx, const bfraw* __restrict__ WoB, float* __restrict__ C) {
    const int m0 = blockIdx.x * 128, n0 = blockIdx.y * 128;
    f32x4 acc[4][4];
    gemm128(Ctx, WoB, m0, n0, acc);
    const int lane = threadIdx.x & 63, wave = threadIdx.x >> 6;
    const int lrow = lane & 15, quad = lane >> 4;
    const int wy = wave >> 1, wx = wave & 1;
    #pragma unroll
    for (int mi = 0; mi < 4; mi++)
        #pragma unroll
        for (int ni = 0; ni < 4; ni++)
            #pragma unroll
            for (int i = 0; i < 4; i++) {
                int m = m0 + wy * 64 + mi * 16 + quad * 4 + i;
                int n = n0 + wx * 64 + ni * 16 + lrow;
                C[m * DIM + n] = acc[mi][ni][i];
            }
}

// ---------------- residual + LayerNorm (fp32) ----------------
__global__ __launch_bounds__(256) void ln_kernel(
        const float* __restrict__ C, const float* __restrict__ Xq,
        const float* __restrict__ gamma, const float* __restrict__ beta,
        float* __restrict__ out) {
    __shared__ float rbuf[4];
    const int m = blockIdx.x, tid = threadIdx.x;
    const float* crow = C + m * DIM;
    const float* xrow = Xq + m * DIM;
    float v[4]; float s = 0.f, s2 = 0.f;
    #pragma unroll
    for (int i = 0; i < 4; i++) {
        int d = tid + (i << 8);
        float x = crow[d] + xrow[d];
        v[i] = x; s += x; s2 += x * x;
    }
    float S  = block_reduce(s,  rbuf, 1);
    float S2 = block_reduce(s2, rbuf, 1);
    float mu  = S * (1.0f / DIM);
    float var = S2 * (1.0f / DIM) - mu * mu;
    float rstd = rsqrtf(var + 1e-5f);
    #pragma unroll
    for (int i = 0; i < 4; i++) {
        int d = tid + (i << 8);
        out[m * DIM + d] = (v[i] - mu) * rstd * gamma[d] + beta[d];
    }
}

extern "C" void kernel_launch(void* const* d_in, const int* in_sizes, int n_in,
                              void* d_out, int out_size, void* d_ws, size_t ws_size,
                              hipStream_t stream) {
    const float* Xq    = (const float*)d_in[0];
    const float* Xk    = (const float*)d_in[1];
    const float* Xv    = (const float*)d_in[2];
    const int*   mask  = (const int*)  d_in[3];
    const float* Wq    = (const float*)d_in[4];
    const float* Wk    = (const float*)d_in[5];
    const float* Wv    = (const float*)d_in[6];
    const float* Wo    = (const float*)d_in[7];
    const float* gamma = (const float*)d_in[8];
    const float* beta  = (const float*)d_in[9];
    float* out = (float*)d_out;

    char* ws = (char*)d_ws;
    bfraw* Xb   = (bfraw*)(ws);
    bfraw* Wb   = (bfraw*)(ws + (24u << 20));
    bfraw* Qp   = (bfraw*)(ws + (32u << 20));
    bfraw* Kp   = (bfraw*)(ws + (40u << 20));
    bfraw* Vt   = (bfraw*)(ws + (48u << 20));
    bfraw* Ctx  = (bfraw*)(ws + (56u << 20));
    float* C    = (float*)(ws);
    float* Scum = (float*)(ws + (16u << 20));

    dim3 blk(256);
    cvt_kernel<<<dim3(MROWS * DIM / (256 * 8), 7), blk, 0, stream>>>(Xq, Xk, Xv, Wq, Wk, Wv, Wo, Xb, Wb);
    qkv_gemm  <<<dim3(MROWS / 128, DIM / 128, 3),  blk, 0, stream>>>(Xb, Wb, Qp, Kp, Vt);
    vsum_kernel<<<dim3(BATCH * NH),                blk, 0, stream>>>(Vt, Scum);
    attn_flash<<<dim3(BATCH * NH, SEQ / 64),       blk, 0, stream>>>(Qp, Kp, Vt, Scum, mask, Ctx);
    out_gemm  <<<dim3(MROWS / 128, DIM / 128),     blk, 0, stream>>>(Ctx, Wb + 3 * (DIM * DIM), C);
    ln_kernel <<<dim3(MROWS),                      blk, 0, stream>>>(C, Xq, gamma, beta, out);
}

// Round 8
// 229.315 us; speedup vs baseline: 1.1526x; 1.0292x over previous
//
#include <hip/hip_runtime.h>

#define NH    16
#define DK    64
#define DIM   1024
#define BATCH 2
#define SEQ   2048
#define MROWS (BATCH*SEQ)   // 4096
#define QSCALE 0.18033688011112043f   // 0.125 * log2(e): folded into Q projection
#define SENT   -44.0f                 // sentinel in log2 domain; exp2(-44)=5.68e-14
#define PCONST 5.684341886080802e-14f // exp2(-44)

typedef unsigned short bfraw;
typedef __attribute__((ext_vector_type(8))) __bf16 bf16x8;
typedef __attribute__((ext_vector_type(8))) unsigned short u16x8;
typedef __attribute__((ext_vector_type(4))) float f32x4;

__device__ __forceinline__ float bf2f(bfraw u) {
    union { unsigned int i; float f; } x; x.i = ((unsigned int)u) << 16; return x.f;
}
__device__ __forceinline__ bfraw f2bf(float f) {          // RNE
    union { float f; unsigned int i; } x; x.f = f;
    unsigned int r = x.i + 0x7FFFu + ((x.i >> 16) & 1u);
    return (bfraw)(r >> 16);
}
__device__ __forceinline__ bfraw f2bf_trunc(float f) {    // truncate (P only; bias cancels in normalize)
    union { float f; unsigned int i; } x; x.f = f;
    return (bfraw)(x.i >> 16);
}
__device__ __forceinline__ float fexp2(float x) {
#if __has_builtin(__builtin_amdgcn_exp2f)
    return __builtin_amdgcn_exp2f(x);
#else
    return exp2f(x);
#endif
}

__device__ __forceinline__ float block_reduce(float val, float* rbuf, int op) {
    const int lane = threadIdx.x & 63, wave = threadIdx.x >> 6;
    #pragma unroll
    for (int off = 32; off; off >>= 1) {
        float o = __shfl_xor(val, off, 64);
        val = op ? (val + o) : fmaxf(val, o);
    }
    if (lane == 0) rbuf[wave] = val;
    __syncthreads();
    float r = op ? (rbuf[0] + rbuf[1] + rbuf[2] + rbuf[3])
                 : fmaxf(fmaxf(rbuf[0], rbuf[1]), fmaxf(rbuf[2], rbuf[3]));
    __syncthreads();
    return r;
}

// ---------------- fp32 -> bf16 convert pass ----------------
__global__ __launch_bounds__(256) void cvt_kernel(
        const float* __restrict__ x0, const float* __restrict__ x1, const float* __restrict__ x2,
        const float* __restrict__ w0, const float* __restrict__ w1, const float* __restrict__ w2,
        const float* __restrict__ w3, bfraw* __restrict__ Xb, bfraw* __restrict__ Wb) {
    const int t = blockIdx.y;
    const float* src; bfraw* dst; int n;
    if (t < 3) { src = (t == 0) ? x0 : (t == 1) ? x1 : x2; dst = Xb + t * (MROWS * DIM); n = MROWS * DIM; }
    else { int u = t - 3; src = (u == 0) ? w0 : (u == 1) ? w1 : (u == 2) ? w2 : w3;
           dst = Wb + u * (DIM * DIM); n = DIM * DIM; }
    int idx = (blockIdx.x * 256 + threadIdx.x) * 8;
    if (idx >= n) return;
    f32x4 a = *(const f32x4*)(src + idx);
    f32x4 b = *(const f32x4*)(src + idx + 4);
    u16x8 o;
    #pragma unroll
    for (int j = 0; j < 4; j++) { o[j] = f2bf(a[j]); o[4 + j] = f2bf(b[j]); }
    *(u16x8*)(dst + idx) = o;
}

// ---------------- 128x128 MFMA GEMM, BK=64, software-pipelined register staging ----------------
// Tile k+1's global loads issue immediately after the compute barrier, overlapping tile k's
// MFMA + LDS reads (vmcnt waited only at next iteration's ds_write). XOR-swizzled unpadded
// LDS (chunk ^= row&7, applied identically on write & read): conflict-free b128 ops.
__device__ __forceinline__ void gemm128(const bfraw* __restrict__ A, const bfraw* __restrict__ B,
                                        int m0, int n0, f32x4 acc[4][4]) {
    __shared__ __align__(16) bfraw As[128 * 64];
    __shared__ __align__(16) bfraw Bs[128 * 64];
    const int tid = threadIdx.x, wave = tid >> 6;
    const int lane = tid & 63, lrow = lane & 15, quad = lane >> 4;
    const int wy = wave >> 1, wx = wave & 1;
    const int swz = lrow & 7;
    // staging: row srow & srow+64; 16 elems (2 chunks) per row per thread
    const int srow = tid >> 2;
    const int cg0  = (tid & 3) << 1;          // global chunk {0,2,4,6}
    const int gc   = cg0 << 3;                // elem offset {0,16,32,48}
    const int e7   = srow & 7;                // (srow+64)&7 == srow&7
    const int o0 = ((cg0 ^ e7) << 3), o1 = (((cg0 | 1) ^ e7) << 3);

    u16x8 ha[4], hb[4];
    const bfraw* pa0 = A + (m0 + srow) * DIM + gc;
    const bfraw* pa1 = A + (m0 + 64 + srow) * DIM + gc;
    const bfraw* pb0 = B + (n0 + srow) * DIM + gc;
    const bfraw* pb1 = B + (n0 + 64 + srow) * DIM + gc;

    #pragma unroll
    for (int i = 0; i < 4; i++)
        #pragma unroll
        for (int j = 0; j < 4; j++) { f32x4 z = {0.f, 0.f, 0.f, 0.f}; acc[i][j] = z; }

    // prologue load (k0 = 0)
    ha[0] = *(const u16x8*)(pa0);     ha[1] = *(const u16x8*)(pa0 + 8);
    ha[2] = *(const u16x8*)(pa1);     ha[3] = *(const u16x8*)(pa1 + 8);
    hb[0] = *(const u16x8*)(pb0);     hb[1] = *(const u16x8*)(pb0 + 8);
    hb[2] = *(const u16x8*)(pb1);     hb[3] = *(const u16x8*)(pb1 + 8);

    for (int k0 = 0; k0 < DIM; k0 += 64) {
        __syncthreads();                            // prior iter's LDS reads done
        *(u16x8*)&As[srow * 64 + o0]        = ha[0];
        *(u16x8*)&As[srow * 64 + o1]        = ha[1];
        *(u16x8*)&As[(64 + srow) * 64 + o0] = ha[2];
        *(u16x8*)&As[(64 + srow) * 64 + o1] = ha[3];
        *(u16x8*)&Bs[srow * 64 + o0]        = hb[0];
        *(u16x8*)&Bs[srow * 64 + o1]        = hb[1];
        *(u16x8*)&Bs[(64 + srow) * 64 + o0] = hb[2];
        *(u16x8*)&Bs[(64 + srow) * 64 + o1] = hb[3];
        __syncthreads();
        if (k0 + 64 < DIM) {                        // prefetch k+1: overlaps MFMA below
            const int k1 = k0 + 64;
            ha[0] = *(const u16x8*)(pa0 + k1);     ha[1] = *(const u16x8*)(pa0 + k1 + 8);
            ha[2] = *(const u16x8*)(pa1 + k1);     ha[3] = *(const u16x8*)(pa1 + k1 + 8);
            hb[0] = *(const u16x8*)(pb0 + k1);     hb[1] = *(const u16x8*)(pb0 + k1 + 8);
            hb[2] = *(const u16x8*)(pb1 + k1);     hb[3] = *(const u16x8*)(pb1 + k1 + 8);
        }
        #pragma unroll
        for (int ks = 0; ks < 2; ks++) {
            const int c = (ks << 2) | quad;
            bf16x8 af[4], bfg[4];
            #pragma unroll
            for (int mi = 0; mi < 4; mi++)
                af[mi] = *(const bf16x8*)&As[(wy * 64 + mi * 16 + lrow) * 64 + ((c ^ swz) << 3)];
            #pragma unroll
            for (int ni = 0; ni < 4; ni++)
                bfg[ni] = *(const bf16x8*)&Bs[(wx * 64 + ni * 16 + lrow) * 64 + ((c ^ swz) << 3)];
            #pragma unroll
            for (int mi = 0; mi < 4; mi++)
                #pragma unroll
                for (int ni = 0; ni < 4; ni++)
                    acc[mi][ni] = __builtin_amdgcn_mfma_f32_16x16x32_bf16(af[mi], bfg[ni], acc[mi][ni], 0, 0, 0);
        }
    }
}

// ---------------- QKV projection ----------------
__global__ __launch_bounds__(256) void qkv_gemm(
        const bfraw* __restrict__ Xb, const bfraw* __restrict__ Wb,
        bfraw* __restrict__ Qp, bfraw* __restrict__ Kp, bfraw* __restrict__ Vt) {
    const int which = blockIdx.z;
    const bfraw* A = Xb + which * (MROWS * DIM);
    const bfraw* B = Wb + which * (DIM * DIM);
    bfraw* O = (which == 0) ? Qp : (which == 1) ? Kp : Vt;
    const int m0 = blockIdx.x * 128, n0 = blockIdx.y * 128;
    f32x4 acc[4][4];
    gemm128(A, B, m0, n0, acc);
    const int lane = threadIdx.x & 63, wave = threadIdx.x >> 6;
    const int lrow = lane & 15, quad = lane >> 4;
    const int wy = wave >> 1, wx = wave & 1;
    const float scale = (which == 0) ? QSCALE : 1.0f;
    #pragma unroll
    for (int mi = 0; mi < 4; mi++)
        #pragma unroll
        for (int ni = 0; ni < 4; ni++)
            #pragma unroll
            for (int i = 0; i < 4; i++) {
                int m = m0 + wy * 64 + mi * 16 + quad * 4 + i;
                int n = n0 + wx * 64 + ni * 16 + lrow;
                int b = m >> 11, s = m & (SEQ - 1), h = n >> 6, kk = n & (DK - 1);
                bfraw v = f2bf(acc[mi][ni][i] * scale);
                if (which == 2) O[(((b * NH + h) * DK) + kk) * SEQ + s] = v;
                else            O[(((b * NH + h) * SEQ) + s) * DK + kk] = v;
            }
}

// ---------------- V tile-boundary prefix sums ----------------
__global__ __launch_bounds__(256) void vsum_kernel(const bfraw* __restrict__ Vt,
                                                   float* __restrict__ Scum) {
    __shared__ float Ts[32][65];
    const int bh = blockIdx.x, tid = threadIdx.x;
    const int d = tid & 63, part = tid >> 6;
    const bfraw* vrow = Vt + (bh * DK + d) * SEQ;
    for (int qt = part * 8; qt < part * 8 + 8; qt++) {
        float s = 0.f;
        #pragma unroll
        for (int j = 0; j < 64; j += 8) {
            u16x8 v = *(const u16x8*)(vrow + qt * 64 + j);
            #pragma unroll
            for (int e = 0; e < 8; e++) s += bf2f(v[e]);
        }
        Ts[qt][d] = s;
    }
    __syncthreads();
    if (tid < 64) {
        float run = 0.f;
        for (int qt = 0; qt < 32; qt++) {
            Scum[(bh * 32 + qt) * 64 + tid] = run;
            run += Ts[qt][tid];
        }
    }
}

// ---------------- flash MFMA attention (r7: register staging + swizzled LDS) ----------------
__global__ __launch_bounds__(256) void attn_flash(
        const bfraw* __restrict__ Qp, const bfraw* __restrict__ Kp, const bfraw* __restrict__ Vt,
        const float* __restrict__ Scum, const int* __restrict__ mask, bfraw* __restrict__ Ctx) {
    __shared__ __align__(16) bfraw Ks[64 * 64];
    __shared__ __align__(16) bfraw Vs[64 * 64];
    __shared__ __align__(16) bfraw Pw[4][16 * 68];
    __shared__ unsigned short Mk[SEQ];
    const int bh = blockIdx.x, yy = blockIdx.y;
    const int gg = yy >> 3, jj = yy & 7;   // CU-stacked groups {j,31-j,8+j,23-j}: const total work
    const int qt = (gg == 0) ? jj : (gg == 1) ? (31 - jj) : (gg == 2) ? (8 + jj) : (23 - jj);
    const int b = bh >> 4, h = bh & 15;
    const int tid = threadIdx.x, wave = tid >> 6, lane = tid & 63;
    const int lrow = lane & 15, quad = lane >> 4;
    const int baseK = ((b * NH + h) * SEQ) * DK;
    const int baseV = ((b * NH + h) * DK) * SEQ;
    const int qbase = qt * 64 + wave * 16;
    const int diagKt = qt * 64;
    const int ldr = tid >> 2;
    const int cg0 = (tid & 3) << 1;
    const int ldc = cg0 << 3;
    const int e7 = ldr & 7;
    const int cl0 = ((cg0 ^ e7) << 3), cl1 = (((cg0 | 1) ^ e7) << 3);

    for (int i = tid; i < SEQ; i += 256) Mk[i] = (unsigned short)(mask[b * SEQ + i] != 0);

    bf16x8 qf[2];
    qf[0] = *(const bf16x8*)(Qp + baseK + (qbase + lrow) * DK + quad * 8);
    qf[1] = *(const bf16x8*)(Qp + baseK + (qbase + lrow) * DK + 32 + quad * 8);

    f32x4 O[4]; float lsum[4];
    #pragma unroll
    for (int n = 0; n < 4; n++) {
        float base = PCONST * Scum[(bh * 32 + qt) * 64 + n * 16 + lrow];
        #pragma unroll
        for (int i = 0; i < 4; i++) O[n][i] = base;
    }
    #pragma unroll
    for (int i = 0; i < 4; i++) lsum[i] = 0.f;

    __syncthreads();                                    // Mk visible

    for (int kt0 = diagKt; kt0 < SEQ; kt0 += 64) {
        u16x8 k0 = *(const u16x8*)(Kp + baseK + (kt0 + ldr) * DK + ldc);
        u16x8 k1 = *(const u16x8*)(Kp + baseK + (kt0 + ldr) * DK + ldc + 8);
        u16x8 v0 = *(const u16x8*)(Vt + baseV + ldr * SEQ + kt0 + ldc);
        u16x8 v1 = *(const u16x8*)(Vt + baseV + ldr * SEQ + kt0 + ldc + 8);
        __syncthreads();                                // prior tile's LDS reads done
        *(u16x8*)&Ks[ldr * 64 + cl0] = k0;
        *(u16x8*)&Ks[ldr * 64 + cl1] = k1;
        *(u16x8*)&Vs[ldr * 64 + cl0] = v0;
        *(u16x8*)&Vs[ldr * 64 + cl1] = v1;
        __syncthreads();

        f32x4 S[4];
        #pragma unroll
        for (int n = 0; n < 4; n++) {
            const int s = n * 16 + lrow;
            f32x4 z = {0.f, 0.f, 0.f, 0.f};
            #pragma unroll
            for (int ks = 0; ks < 2; ks++) {
                bf16x8 kb = *(const bf16x8*)&Ks[s * 64 + ((((ks << 2) | quad) ^ (s & 7)) << 3)];
                z = __builtin_amdgcn_mfma_f32_16x16x32_bf16(qf[ks], kb, z, 0, 0, 0);
            }
            S[n] = z;
        }

        float p[4][4];
        if (kt0 == diagKt) {
            #pragma unroll
            for (int n = 0; n < 4; n++) {
                int s = kt0 + n * 16 + lrow;
                bool mk = (Mk[s] != 0);
                #pragma unroll
                for (int i = 0; i < 4; i++) {
                    bool valid = mk && (s > qbase + quad * 4 + i);
                    p[n][i] = fexp2(valid ? S[n][i] : SENT);
                }
            }
        } else {
            #pragma unroll
            for (int n = 0; n < 4; n++) {
                bool mk = (Mk[kt0 + n * 16 + lrow] != 0);
                #pragma unroll
                for (int i = 0; i < 4; i++) p[n][i] = fexp2(mk ? S[n][i] : SENT);
            }
        }

        #pragma unroll
        for (int i = 0; i < 4; i++) lsum[i] += (p[0][i] + p[1][i]) + (p[2][i] + p[3][i]);

        #pragma unroll
        for (int n = 0; n < 4; n++)
            #pragma unroll
            for (int i = 0; i < 4; i++)
                Pw[wave][(quad * 4 + i) * 68 + n * 16 + lrow] = f2bf_trunc(p[n][i]);

        bf16x8 pa0 = *(const bf16x8*)&Pw[wave][lrow * 68 + quad * 8];
        bf16x8 pa1 = *(const bf16x8*)&Pw[wave][lrow * 68 + 32 + quad * 8];
        #pragma unroll
        for (int n = 0; n < 4; n++) {
            const int d = n * 16 + lrow;
            #pragma unroll
            for (int ks = 0; ks < 2; ks++) {
                bf16x8 vb = *(const bf16x8*)&Vs[d * 64 + ((((ks << 2) | quad) ^ (d & 7)) << 3)];
                O[n] = __builtin_amdgcn_mfma_f32_16x16x32_bf16(ks ? pa1 : pa0, vb, O[n], 0, 0, 0);
            }
        }
    }

    float inv[4];
    #pragma unroll
    for (int i = 0; i < 4; i++) {
        float r = lsum[i];
        #pragma unroll
        for (int off = 1; off < 16; off <<= 1) r += __shfl_xor(r, off, 64);
        inv[i] = 1.0f / (r + (float)diagKt * PCONST);
    }
    #pragma unroll
    for (int n = 0; n < 4; n++)
        #pragma unroll
        for (int i = 0; i < 4; i++)
            Ctx[(b * SEQ + qbase + quad * 4 + i) * DIM + h * DK + n * 16 + lrow] = f2bf(O[n][i] * inv[i]);
}

// ---------------- output projection ----------------
__global__ __launch_bounds__(256) void out_gemm(
        const bfraw* __restrict__ Ctx, const bfraw* __restrict__ WoB, float* __restrict__ C) {
    const int m0 = blockIdx.x * 128, n0 = blockIdx.y * 128;
    f32x4 acc[4][4];
    gemm128(Ctx, WoB, m0, n0, acc);
    const int lane = threadIdx.x & 63, wave = threadIdx.x >> 6;
    const int lrow = lane & 15, quad = lane >> 4;
    const int wy = wave >> 1, wx = wave & 1;
    #pragma unroll
    for (int mi = 0; mi < 4; mi++)
        #pragma unroll
        for (int ni = 0; ni < 4; ni++)
            #pragma unroll
            for (int i = 0; i < 4; i++) {
                int m = m0 + wy * 64 + mi * 16 + quad * 4 + i;
                int n = n0 + wx * 64 + ni * 16 + lrow;
                C[m * DIM + n] = acc[mi][ni][i];
            }
}

// ---------------- residual + LayerNorm (fp32) ----------------
__global__ __launch_bounds__(256) void ln_kernel(
        const float* __restrict__ C, const float* __restrict__ Xq,
        const float* __restrict__ gamma, const float* __restrict__ beta,
        float* __restrict__ out) {
    __shared__ float rbuf[4];
    const int m = blockIdx.x, tid = threadIdx.x;
    const float* crow = C + m * DIM;
    const float* xrow = Xq + m * DIM;
    float v[4]; float s = 0.f, s2 = 0.f;
    #pragma unroll
    for (int i = 0; i < 4; i++) {
        int d = tid + (i << 8);
        float x = crow[d] + xrow[d];
        v[i] = x; s += x; s2 += x * x;
    }
    float S  = block_reduce(s,  rbuf, 1);
    float S2 = block_reduce(s2, rbuf, 1);
    float mu  = S * (1.0f / DIM);
    float var = S2 * (1.0f / DIM) - mu * mu;
    float rstd = rsqrtf(var + 1e-5f);
    #pragma unroll
    for (int i = 0; i < 4; i++) {
        int d = tid + (i << 8);
        out[m * DIM + d] = (v[i] - mu) * rstd * gamma[d] + beta[d];
    }
}

extern "C" void kernel_launch(void* const* d_in, const int* in_sizes, int n_in,
                              void* d_out, int out_size, void* d_ws, size_t ws_size,
                              hipStream_t stream) {
    const float* Xq    = (const float*)d_in[0];
    const float* Xk    = (const float*)d_in[1];
    const float* Xv    = (const float*)d_in[2];
    const int*   mask  = (const int*)  d_in[3];
    const float* Wq    = (const float*)d_in[4];
    const float* Wk    = (const float*)d_in[5];
    const float* Wv    = (const float*)d_in[6];
    const float* Wo    = (const float*)d_in[7];
    const float* gamma = (const float*)d_in[8];
    const float* beta  = (const float*)d_in[9];
    float* out = (float*)d_out;

    char* ws = (char*)d_ws;
    bfraw* Xb   = (bfraw*)(ws);
    bfraw* Wb   = (bfraw*)(ws + (24u << 20));
    bfraw* Qp   = (bfraw*)(ws + (32u << 20));
    bfraw* Kp   = (bfraw*)(ws + (40u << 20));
    bfraw* Vt   = (bfraw*)(ws + (48u << 20));
    bfraw* Ctx  = (bfraw*)(ws + (56u << 20));
    float* C    = (float*)(ws);
    float* Scum = (float*)(ws + (16u << 20));

    dim3 blk(256);
    cvt_kernel<<<dim3(MROWS * DIM / (256 * 8), 7), blk, 0, stream>>>(Xq, Xk, Xv, Wq, Wk, Wv, Wo, Xb, Wb);
    qkv_gemm  <<<dim3(MROWS / 128, DIM / 128, 3),  blk, 0, stream>>>(Xb, Wb, Qp, Kp, Vt);
    vsum_kernel<<<dim3(BATCH * NH),                blk, 0, stream>>>(Vt, Scum);
    attn_flash<<<dim3(BATCH * NH, SEQ / 64),       blk, 0, stream>>>(Qp, Kp, Vt, Scum, mask, Ctx);
    out_gemm  <<<dim3(MROWS / 128, DIM / 128),     blk, 0, stream>>>(Ctx, Wb + 3 * (DIM * DIM), C);
    ln_kernel <<<dim3(MROWS),                      blk, 0, stream>>>(C, Xq, gamma, beta, out);
}

// Round 9
// 224.057 us; speedup vs baseline: 1.1797x; 1.0235x over previous
//
#include <hip/hip_runtime.h>

#define NH    16
#define DK    64
#define DIM   1024
#define BATCH 2
#define SEQ   2048
#define MROWS (BATCH*SEQ)   // 4096
#define QSCALE 0.18033688011112043f   // 0.125 * log2(e): folded into Q projection
#define SENT   -44.0f                 // sentinel in log2 domain; exp2(-44)=5.68e-14
#define PCONST 5.684341886080802e-14f // exp2(-44)

typedef unsigned short bfraw;
typedef __attribute__((ext_vector_type(8))) __bf16 bf16x8;
typedef __attribute__((ext_vector_type(4))) __bf16 bf16x4;
typedef __attribute__((ext_vector_type(8))) unsigned short u16x8;
typedef __attribute__((ext_vector_type(4))) unsigned short u16x4;
typedef __attribute__((ext_vector_type(4))) short s16x4;
typedef __attribute__((ext_vector_type(4))) float f32x4;

__device__ __forceinline__ float bf2f(bfraw u) {
    union { unsigned int i; float f; } x; x.i = ((unsigned int)u) << 16; return x.f;
}
__device__ __forceinline__ bfraw f2bf(float f) {          // RNE
    union { float f; unsigned int i; } x; x.f = f;
    unsigned int r = x.i + 0x7FFFu + ((x.i >> 16) & 1u);
    return (bfraw)(r >> 16);
}
__device__ __forceinline__ bfraw f2bf_trunc(float f) {    // truncate (P only; bias cancels in normalize)
    union { float f; unsigned int i; } x; x.f = f;
    return (bfraw)(x.i >> 16);
}
__device__ __forceinline__ float fexp2(float x) {
#if __has_builtin(__builtin_amdgcn_exp2f)
    return __builtin_amdgcn_exp2f(x);
#else
    return exp2f(x);
#endif
}

// K=16 bf16 MFMA: D = A(16x16) * B(16x16) + C. Name hedged across ROCm spellings;
// instruction v_mfma_f32_16x16x16_bf16 is ISA-confirmed on gfx950.
__device__ __forceinline__ f32x4 mfma16(s16x4 a, s16x4 b, f32x4 c) {
#if __has_builtin(__builtin_amdgcn_mfma_f32_16x16x16_bf16)
    union { s16x4 s; bf16x4 h; } ua, ub; ua.s = a; ub.s = b;
    return __builtin_amdgcn_mfma_f32_16x16x16_bf16(ua.h, ub.h, c, 0, 0, 0);
#elif __has_builtin(__builtin_amdgcn_mfma_f32_16x16x16bf16_1k)
    return __builtin_amdgcn_mfma_f32_16x16x16bf16_1k(a, b, c, 0, 0, 0);
#else
    asm("v_mfma_f32_16x16x16_bf16 %0, %1, %2, %0" : "+v"(c) : "v"(a), "v"(b));
    return c;
#endif
}

__device__ __forceinline__ float block_reduce(float val, float* rbuf, int op) {
    const int lane = threadIdx.x & 63, wave = threadIdx.x >> 6;
    #pragma unroll
    for (int off = 32; off; off >>= 1) {
        float o = __shfl_xor(val, off, 64);
        val = op ? (val + o) : fmaxf(val, o);
    }
    if (lane == 0) rbuf[wave] = val;
    __syncthreads();
    float r = op ? (rbuf[0] + rbuf[1] + rbuf[2] + rbuf[3])
                 : fmaxf(fmaxf(rbuf[0], rbuf[1]), fmaxf(rbuf[2], rbuf[3]));
    __syncthreads();
    return r;
}

// ---------------- fp32 -> bf16 convert pass ----------------
__global__ __launch_bounds__(256) void cvt_kernel(
        const float* __restrict__ x0, const float* __restrict__ x1, const float* __restrict__ x2,
        const float* __restrict__ w0, const float* __restrict__ w1, const float* __restrict__ w2,
        const float* __restrict__ w3, bfraw* __restrict__ Xb, bfraw* __restrict__ Wb) {
    const int t = blockIdx.y;
    const float* src; bfraw* dst; int n;
    if (t < 3) { src = (t == 0) ? x0 : (t == 1) ? x1 : x2; dst = Xb + t * (MROWS * DIM); n = MROWS * DIM; }
    else { int u = t - 3; src = (u == 0) ? w0 : (u == 1) ? w1 : (u == 2) ? w2 : w3;
           dst = Wb + u * (DIM * DIM); n = DIM * DIM; }
    int idx = (blockIdx.x * 256 + threadIdx.x) * 8;
    if (idx >= n) return;
    f32x4 a = *(const f32x4*)(src + idx);
    f32x4 b = *(const f32x4*)(src + idx + 4);
    u16x8 o;
    #pragma unroll
    for (int j = 0; j < 4; j++) { o[j] = f2bf(a[j]); o[4 + j] = f2bf(b[j]); }
    *(u16x8*)(dst + idx) = o;
}

// ---------------- 128x128 MFMA GEMM, BK=64, software-pipelined register staging ----------------
__device__ __forceinline__ void gemm128(const bfraw* __restrict__ A, const bfraw* __restrict__ B,
                                        int m0, int n0, f32x4 acc[4][4]) {
    __shared__ __align__(16) bfraw As[128 * 64];
    __shared__ __align__(16) bfraw Bs[128 * 64];
    const int tid = threadIdx.x, wave = tid >> 6;
    const int lane = tid & 63, lrow = lane & 15, quad = lane >> 4;
    const int wy = wave >> 1, wx = wave & 1;
    const int swz = lrow & 7;
    const int srow = tid >> 2;
    const int cg0  = (tid & 3) << 1;
    const int gc   = cg0 << 3;
    const int e7   = srow & 7;
    const int o0 = ((cg0 ^ e7) << 3), o1 = (((cg0 | 1) ^ e7) << 3);

    u16x8 ha[4], hb[4];
    const bfraw* pa0 = A + (m0 + srow) * DIM + gc;
    const bfraw* pa1 = A + (m0 + 64 + srow) * DIM + gc;
    const bfraw* pb0 = B + (n0 + srow) * DIM + gc;
    const bfraw* pb1 = B + (n0 + 64 + srow) * DIM + gc;

    #pragma unroll
    for (int i = 0; i < 4; i++)
        #pragma unroll
        for (int j = 0; j < 4; j++) { f32x4 z = {0.f, 0.f, 0.f, 0.f}; acc[i][j] = z; }

    ha[0] = *(const u16x8*)(pa0);     ha[1] = *(const u16x8*)(pa0 + 8);
    ha[2] = *(const u16x8*)(pa1);     ha[3] = *(const u16x8*)(pa1 + 8);
    hb[0] = *(const u16x8*)(pb0);     hb[1] = *(const u16x8*)(pb0 + 8);
    hb[2] = *(const u16x8*)(pb1);     hb[3] = *(const u16x8*)(pb1 + 8);

    for (int k0 = 0; k0 < DIM; k0 += 64) {
        __syncthreads();
        *(u16x8*)&As[srow * 64 + o0]        = ha[0];
        *(u16x8*)&As[srow * 64 + o1]        = ha[1];
        *(u16x8*)&As[(64 + srow) * 64 + o0] = ha[2];
        *(u16x8*)&As[(64 + srow) * 64 + o1] = ha[3];
        *(u16x8*)&Bs[srow * 64 + o0]        = hb[0];
        *(u16x8*)&Bs[srow * 64 + o1]        = hb[1];
        *(u16x8*)&Bs[(64 + srow) * 64 + o0] = hb[2];
        *(u16x8*)&Bs[(64 + srow) * 64 + o1] = hb[3];
        __syncthreads();
        if (k0 + 64 < DIM) {
            const int k1 = k0 + 64;
            ha[0] = *(const u16x8*)(pa0 + k1);     ha[1] = *(const u16x8*)(pa0 + k1 + 8);
            ha[2] = *(const u16x8*)(pa1 + k1);     ha[3] = *(const u16x8*)(pa1 + k1 + 8);
            hb[0] = *(const u16x8*)(pb0 + k1);     hb[1] = *(const u16x8*)(pb0 + k1 + 8);
            hb[2] = *(const u16x8*)(pb1 + k1);     hb[3] = *(const u16x8*)(pb1 + k1 + 8);
        }
        #pragma unroll
        for (int ks = 0; ks < 2; ks++) {
            const int c = (ks << 2) | quad;
            bf16x8 af[4], bfg[4];
            #pragma unroll
            for (int mi = 0; mi < 4; mi++)
                af[mi] = *(const bf16x8*)&As[(wy * 64 + mi * 16 + lrow) * 64 + ((c ^ swz) << 3)];
            #pragma unroll
            for (int ni = 0; ni < 4; ni++)
                bfg[ni] = *(const bf16x8*)&Bs[(wx * 64 + ni * 16 + lrow) * 64 + ((c ^ swz) << 3)];
            #pragma unroll
            for (int mi = 0; mi < 4; mi++)
                #pragma unroll
                for (int ni = 0; ni < 4; ni++)
                    acc[mi][ni] = __builtin_amdgcn_mfma_f32_16x16x32_bf16(af[mi], bfg[ni], acc[mi][ni], 0, 0, 0);
        }
    }
}

// ---------------- QKV projection ----------------
__global__ __launch_bounds__(256) void qkv_gemm(
        const bfraw* __restrict__ Xb, const bfraw* __restrict__ Wb,
        bfraw* __restrict__ Qp, bfraw* __restrict__ Kp, bfraw* __restrict__ Vt) {
    const int which = blockIdx.z;
    const bfraw* A = Xb + which * (MROWS * DIM);
    const bfraw* B = Wb + which * (DIM * DIM);
    bfraw* O = (which == 0) ? Qp : (which == 1) ? Kp : Vt;
    const int m0 = blockIdx.x * 128, n0 = blockIdx.y * 128;
    f32x4 acc[4][4];
    gemm128(A, B, m0, n0, acc);
    const int lane = threadIdx.x & 63, wave = threadIdx.x >> 6;
    const int lrow = lane & 15, quad = lane >> 4;
    const int wy = wave >> 1, wx = wave & 1;
    const float scale = (which == 0) ? QSCALE : 1.0f;
    #pragma unroll
    for (int mi = 0; mi < 4; mi++)
        #pragma unroll
        for (int ni = 0; ni < 4; ni++)
            #pragma unroll
            for (int i = 0; i < 4; i++) {
                int m = m0 + wy * 64 + mi * 16 + quad * 4 + i;
                int n = n0 + wx * 64 + ni * 16 + lrow;
                int b = m >> 11, s = m & (SEQ - 1), h = n >> 6, kk = n & (DK - 1);
                bfraw v = f2bf(acc[mi][ni][i] * scale);
                if (which == 2) O[(((b * NH + h) * DK) + kk) * SEQ + s] = v;
                else            O[(((b * NH + h) * SEQ) + s) * DK + kk] = v;
            }
}

// ---------------- V tile-boundary prefix sums ----------------
__global__ __launch_bounds__(256) void vsum_kernel(const bfraw* __restrict__ Vt,
                                                   float* __restrict__ Scum) {
    __shared__ float Ts[32][65];
    const int bh = blockIdx.x, tid = threadIdx.x;
    const int d = tid & 63, part = tid >> 6;
    const bfraw* vrow = Vt + (bh * DK + d) * SEQ;
    for (int qt = part * 8; qt < part * 8 + 8; qt++) {
        float s = 0.f;
        #pragma unroll
        for (int j = 0; j < 64; j += 8) {
            u16x8 v = *(const u16x8*)(vrow + qt * 64 + j);
            #pragma unroll
            for (int e = 0; e < 8; e++) s += bf2f(v[e]);
        }
        Ts[qt][d] = s;
    }
    __syncthreads();
    if (tid < 64) {
        float run = 0.f;
        for (int qt = 0; qt < 32; qt++) {
            Scum[(bh * 32 + qt) * 64 + tid] = run;
            run += Ts[qt][tid];
        }
    }
}

// ---------------- flash MFMA attention: transposed-S, in-register P, K/V dbuf ----------------
// S^T = K*Q^T (A=K-frag, B=Q-frag): C/D layout (row=s=quad*4+i, col=q=lrow) IS the
// B-operand layout of the K=16 MFMA, so P^T feeds O^T = V^T * P^T directly from
// registers -- no P LDS round-trip. K/V double-buffered: ONE barrier per tile.
__global__ __launch_bounds__(256) void attn_flash(
        const bfraw* __restrict__ Qp, const bfraw* __restrict__ Kp, const bfraw* __restrict__ Vt,
        const float* __restrict__ Scum, const int* __restrict__ mask, bfraw* __restrict__ Ctx) {
    __shared__ __align__(16) bfraw Ks[2][64 * 64];
    __shared__ __align__(16) bfraw Vs[2][64 * 64];
    __shared__ unsigned short Mk[SEQ];
    const int bh = blockIdx.x, yy = blockIdx.y;
    const int gg = yy >> 3, jj = yy & 7;   // CU-stacked groups {j,31-j,8+j,23-j}: const total work
    const int qt = (gg == 0) ? jj : (gg == 1) ? (31 - jj) : (gg == 2) ? (8 + jj) : (23 - jj);
    const int b = bh >> 4, h = bh & 15;
    const int tid = threadIdx.x, wave = tid >> 6, lane = tid & 63;
    const int lrow = lane & 15, quad = lane >> 4;
    const int baseK = ((b * NH + h) * SEQ) * DK;
    const int baseV = ((b * NH + h) * DK) * SEQ;
    const int qbase = qt * 64 + wave * 16;
    const int q_ln  = qbase + lrow;            // this lane's q (col of S^T)
    const int diagKt = qt * 64;
    const int ldr = tid >> 2;
    const int cg0 = (tid & 3) << 1;
    const int ldc = cg0 << 3;
    const int e7 = ldr & 7;
    const int cl0 = ((cg0 ^ e7) << 3), cl1 = (((cg0 | 1) ^ e7) << 3);

    for (int i = tid; i < SEQ; i += 256) Mk[i] = (unsigned short)(mask[b * SEQ + i] != 0);

    bf16x8 qf[2];                              // B-operand: Q[q=lrow][k=ks*32+quad*8+j]
    qf[0] = *(const bf16x8*)(Qp + baseK + (qbase + lrow) * DK + quad * 8);
    qf[1] = *(const bf16x8*)(Qp + baseK + (qbase + lrow) * DK + 32 + quad * 8);

    f32x4 Oa[4];                               // O^T: row=d=nd*16+quad*4+i, col=q=lrow
    #pragma unroll
    for (int nd = 0; nd < 4; nd++) {
        f32x4 sv = *(const f32x4*)&Scum[(bh * 32 + qt) * 64 + nd * 16 + quad * 4];
        #pragma unroll
        for (int i = 0; i < 4; i++) Oa[nd][i] = PCONST * sv[i];
    }
    float lsum = 0.f;

    const int nt = (SEQ - diagKt) >> 6;
    int kt0 = diagKt;
    u16x8 k0 = *(const u16x8*)(Kp + baseK + (kt0 + ldr) * DK + ldc);
    u16x8 k1 = *(const u16x8*)(Kp + baseK + (kt0 + ldr) * DK + ldc + 8);
    u16x8 v0 = *(const u16x8*)(Vt + baseV + ldr * SEQ + kt0 + ldc);
    u16x8 v1 = *(const u16x8*)(Vt + baseV + ldr * SEQ + kt0 + ldc + 8);

    for (int t = 0; t < nt; t++, kt0 += 64) {
        bfraw* Kb = Ks[t & 1];
        bfraw* Vb = Vs[t & 1];
        *(u16x8*)&Kb[ldr * 64 + cl0] = k0;
        *(u16x8*)&Kb[ldr * 64 + cl1] = k1;
        *(u16x8*)&Vb[ldr * 64 + cl0] = v0;
        *(u16x8*)&Vb[ldr * 64 + cl1] = v1;
        if (t + 1 < nt) {                      // prefetch overlaps barrier + compute
            const int kn = kt0 + 64;
            k0 = *(const u16x8*)(Kp + baseK + (kn + ldr) * DK + ldc);
            k1 = *(const u16x8*)(Kp + baseK + (kn + ldr) * DK + ldc + 8);
            v0 = *(const u16x8*)(Vt + baseV + ldr * SEQ + kn + ldc);
            v1 = *(const u16x8*)(Vt + baseV + ldr * SEQ + kn + ldc + 8);
        }
        __syncthreads();                       // single barrier per tile (dbuf)

        s16x4 pb[4];
        #pragma unroll
        for (int n = 0; n < 4; n++) {
            const int srow = n * 16 + lrow;    // A-operand row (= s within tile)
            bf16x8 kfa = *(const bf16x8*)&Kb[srow * 64 + ((quad ^ (lrow & 7)) << 3)];
            bf16x8 kfb = *(const bf16x8*)&Kb[srow * 64 + (((4 | quad) ^ (lrow & 7)) << 3)];
            f32x4 z = {0.f, 0.f, 0.f, 0.f};
            z = __builtin_amdgcn_mfma_f32_16x16x32_bf16(kfa, qf[0], z, 0, 0, 0);
            z = __builtin_amdgcn_mfma_f32_16x16x32_bf16(kfb, qf[1], z, 0, 0, 0);
            u16x4 pu;
            if (t == 0) {                      // diagonal tile: full causal compare
                #pragma unroll
                for (int i = 0; i < 4; i++) {
                    int s = kt0 + n * 16 + quad * 4 + i;
                    bool valid = (Mk[s] != 0) && (s > q_ln);
                    float p = fexp2(valid ? z[i] : SENT);
                    lsum += p; pu[i] = f2bf_trunc(p);
                }
            } else {                           // strictly-future: padding mask only
                #pragma unroll
                for (int i = 0; i < 4; i++) {
                    int s = kt0 + n * 16 + quad * 4 + i;
                    float p = fexp2(Mk[s] ? z[i] : SENT);
                    lsum += p; pu[i] = f2bf_trunc(p);
                }
            }
            union { u16x4 u; s16x4 s; } cv; cv.u = pu; pb[n] = cv.s;
        }

        #pragma unroll
        for (int nd = 0; nd < 4; nd++) {
            const int d = nd * 16 + lrow;
            #pragma unroll
            for (int sc = 0; sc < 4; sc++) {
                s16x4 vf = *(const s16x4*)&Vb[d * 64
                    + ((((sc << 1) | (quad >> 1)) ^ (d & 7)) << 3) + ((quad & 1) << 2)];
                Oa[nd] = mfma16(vf, pb[sc], Oa[nd]);
            }
        }
    }

    float r = lsum;
    r += __shfl_xor(r, 16, 64);
    r += __shfl_xor(r, 32, 64);
    const float inv = 1.0f / (r + (float)diagKt * PCONST);
    #pragma unroll
    for (int nd = 0; nd < 4; nd++) {
        u16x4 o;
        #pragma unroll
        for (int i = 0; i < 4; i++) o[i] = f2bf(Oa[nd][i] * inv);
        *(u16x4*)&Ctx[(b * SEQ + q_ln) * DIM + h * DK + nd * 16 + quad * 4] = o;
    }
}

// ---------------- output projection ----------------
__global__ __launch_bounds__(256) void out_gemm(
        const bfraw* __restrict__ Ctx, const bfraw* __restrict__ WoB, float* __restrict__ C) {
    const int m0 = blockIdx.x * 128, n0 = blockIdx.y * 128;
    f32x4 acc[4][4];
    gemm128(Ctx, WoB, m0, n0, acc);
    const int lane = threadIdx.x & 63, wave = threadIdx.x >> 6;
    const int lrow = lane & 15, quad = lane >> 4;
    const int wy = wave >> 1, wx = wave & 1;
    #pragma unroll
    for (int mi = 0; mi < 4; mi++)
        #pragma unroll
        for (int ni = 0; ni < 4; ni++)
            #pragma unroll
            for (int i = 0; i < 4; i++) {
                int m = m0 + wy * 64 + mi * 16 + quad * 4 + i;
                int n = n0 + wx * 64 + ni * 16 + lrow;
                C[m * DIM + n] = acc[mi][ni][i];
            }
}

// ---------------- residual + LayerNorm (fp32) ----------------
__global__ __launch_bounds__(256) void ln_kernel(
        const float* __restrict__ C, const float* __restrict__ Xq,
        const float* __restrict__ gamma, const float* __restrict__ beta,
        float* __restrict__ out) {
    __shared__ float rbuf[4];
    const int m = blockIdx.x, tid = threadIdx.x;
    const float* crow = C + m * DIM;
    const float* xrow = Xq + m * DIM;
    float v[4]; float s = 0.f, s2 = 0.f;
    #pragma unroll
    for (int i = 0; i < 4; i++) {
        int d = tid + (i << 8);
        float x = crow[d] + xrow[d];
        v[i] = x; s += x; s2 += x * x;
    }
    float S  = block_reduce(s,  rbuf, 1);
    float S2 = block_reduce(s2, rbuf, 1);
    float mu  = S * (1.0f / DIM);
    float var = S2 * (1.0f / DIM) - mu * mu;
    float rstd = rsqrtf(var + 1e-5f);
    #pragma unroll
    for (int i = 0; i < 4; i++) {
        int d = tid + (i << 8);
        out[m * DIM + d] = (v[i] - mu) * rstd * gamma[d] + beta[d];
    }
}

extern "C" void kernel_launch(void* const* d_in, const int* in_sizes, int n_in,
                              void* d_out, int out_size, void* d_ws, size_t ws_size,
                              hipStream_t stream) {
    const float* Xq    = (const float*)d_in[0];
    const float* Xk    = (const float*)d_in[1];
    const float* Xv    = (const float*)d_in[2];
    const int*   mask  = (const int*)  d_in[3];
    const float* Wq    = (const float*)d_in[4];
    const float* Wk    = (const float*)d_in[5];
    const float* Wv    = (const float*)d_in[6];
    const float* Wo    = (const float*)d_in[7];
    const float* gamma = (const float*)d_in[8];
    const float* beta  = (const float*)d_in[9];
    float* out = (float*)d_out;

    char* ws = (char*)d_ws;
    bfraw* Xb   = (bfraw*)(ws);
    bfraw* Wb   = (bfraw*)(ws + (24u << 20));
    bfraw* Qp   = (bfraw*)(ws + (32u << 20));
    bfraw* Kp   = (bfraw*)(ws + (40u << 20));
    bfraw* Vt   = (bfraw*)(ws + (48u << 20));
    bfraw* Ctx  = (bfraw*)(ws + (56u << 20));
    float* C    = (float*)(ws);
    float* Scum = (float*)(ws + (16u << 20));

    dim3 blk(256);
    cvt_kernel<<<dim3(MROWS * DIM / (256 * 8), 7), blk, 0, stream>>>(Xq, Xk, Xv, Wq, Wk, Wv, Wo, Xb, Wb);
    qkv_gemm  <<<dim3(MROWS / 128, DIM / 128, 3),  blk, 0, stream>>>(Xb, Wb, Qp, Kp, Vt);
    vsum_kernel<<<dim3(BATCH * NH),                blk, 0, stream>>>(Vt, Scum);
    attn_flash<<<dim3(BATCH * NH, SEQ / 64),       blk, 0, stream>>>(Qp, Kp, Vt, Scum, mask, Ctx);
    out_gemm  <<<dim3(MROWS / 128, DIM / 128),     blk, 0, stream>>>(Ctx, Wb + 3 * (DIM * DIM), C);
    ln_kernel <<<dim3(MROWS),                      blk, 0, stream>>>(C, Xq, gamma, beta, out);
}